// Round 1
// baseline (11360.863 us; speedup 1.0000x reference)
//
#include <hip/hip_runtime.h>
#include <hip/hip_bf16.h>
#include <stdint.h>

#define D 512          // D_IN == D_OUT == 512
#define D4 (D / 4)     // 128 float4 per row
#define D8 (D / 8)     // 64 groups of 8

typedef __bf16 bf16x8 __attribute__((ext_vector_type(8)));
typedef float  f32x4  __attribute__((ext_vector_type(4)));

__device__ __forceinline__ unsigned short f2bf(float f) {
    uint32_t u = __float_as_uint(f);
    uint32_t r = u + 0x7fffu + ((u >> 16) & 1u);   // RNE
    return (unsigned short)(r >> 16);
}

__device__ __forceinline__ uint32_t pack2(float lo, float hi) {
    return (uint32_t)f2bf(lo) | ((uint32_t)f2bf(hi) << 16);
}

// ---------------------------------------------------------------- cvt X -> bf16
__global__ __launch_bounds__(256) void cvt_x_kernel(const float4* __restrict__ x,
                                                    uint4* __restrict__ xb,
                                                    long n8) {
    long i = (long)blockIdx.x * 256 + threadIdx.x;   // one thread = 8 elements
    if (i >= n8) return;
    float4 a = x[i * 2];
    float4 b = x[i * 2 + 1];
    uint4 o;
    o.x = pack2(a.x, a.y);
    o.y = pack2(a.z, a.w);
    o.z = pack2(b.x, b.y);
    o.w = pack2(b.z, b.w);
    xb[i] = o;
}

// ------------------------------------------------- transpose + cvt W -> Wt bf16
__global__ __launch_bounds__(256) void cvt_w_kernel(const float* __restrict__ w,
                                                    unsigned short* __restrict__ wt) {
    __shared__ float t[32][33];
    const int tx = threadIdx.x & 31;
    const int ty = threadIdx.x >> 5;       // 0..7
    const int n0 = blockIdx.x * 32;
    const int k0 = blockIdx.y * 32;
#pragma unroll
    for (int i = 0; i < 4; ++i)
        t[ty + i * 8][tx] = w[(long)(k0 + ty + i * 8) * D + n0 + tx];
    __syncthreads();
#pragma unroll
    for (int i = 0; i < 4; ++i)
        wt[(long)(n0 + ty + i * 8) * D + k0 + tx] = f2bf(t[tx][ty + i * 8]);
}

// ------------------------------------------------------------- out[n][d] = b[d]
__global__ __launch_bounds__(256) void init_out_kernel(float4* __restrict__ out,
                                                       const float4* __restrict__ b,
                                                       long n4) {
    long i = (long)blockIdx.x * 256 + threadIdx.x;
    if (i >= n4) return;
    out[i] = b[i & (D4 - 1)];
}

// --------------------------------------------------------- GEMM: Sup = Xb * W
// 128x128 tile, BK=64, 256 threads (4 waves, 2x2), 16x16x32 bf16 MFMA.
// LDS layout XOR-swizzled in 8-element granules to keep ds_read_b128
// conflict-free while matching global_load_lds's "base + lane*16" LDS rule.
__global__ __launch_bounds__(256) void gemm_kernel(const unsigned short* __restrict__ Xb,
                                                   const unsigned short* __restrict__ Wt,
                                                   unsigned short* __restrict__ Sup,
                                                   int M) {
    __shared__ __align__(16) unsigned short As[128 * 64];
    __shared__ __align__(16) unsigned short Bs[128 * 64];
    const int tid  = threadIdx.x;
    const int wv   = tid >> 6;
    const int lane = tid & 63;
    const int tileM = blockIdx.x * 128;
    const int tileN = blockIdx.y * 128;
    const int wm = wv >> 1, wn = wv & 1;

    f32x4 acc[4][4];
#pragma unroll
    for (int i = 0; i < 4; ++i)
#pragma unroll
        for (int j = 0; j < 4; ++j) acc[i][j] = (f32x4)0.0f;

    // staging geometry: chunk = 1024B = 8 rows x (64 bf16 = 128B)
    const int srow = lane >> 3;               // row within chunk (== ldsrow & 7)
    const int sgrn = (lane & 7) ^ srow;       // swizzled source granule
    const int scol = sgrn * 8;                // element col within BK

    // fragment geometry
    const int fm  = lane & 15;
    const int fkq = lane >> 4;                // 0..3

    for (int kt = 0; kt < D; kt += 64) {
        __syncthreads();
#pragma unroll
        for (int i = 0; i < 4; ++i) {
            const int c   = wv * 4 + i;       // chunk 0..15
            const int row = c * 8 + srow;     // 0..127
            int rg = tileM + row;
            rg = (rg < M) ? rg : (M - 1);     // clamp, epilogue masks
            const unsigned short* ga = Xb + (long)rg * D + kt + scol;
            __builtin_amdgcn_global_load_lds(
                (const __attribute__((address_space(1))) void*)ga,
                (__attribute__((address_space(3))) void*)(As + c * 512), 16, 0, 0);
            const unsigned short* gb = Wt + (long)(tileN + row) * D + kt + scol;
            __builtin_amdgcn_global_load_lds(
                (const __attribute__((address_space(1))) void*)gb,
                (__attribute__((address_space(3))) void*)(Bs + c * 512), 16, 0, 0);
        }
        __syncthreads();
#pragma unroll
        for (int kk = 0; kk < 2; ++kk) {
            bf16x8 af[4], bfr[4];
#pragma unroll
            for (int mi = 0; mi < 4; ++mi) {
                const int m = wm * 64 + mi * 16 + fm;
                const int g = (kk * 4 + fkq) ^ (m & 7);
                af[mi] = *(const bf16x8*)(As + m * 64 + g * 8);
            }
#pragma unroll
            for (int ni = 0; ni < 4; ++ni) {
                const int n = wn * 64 + ni * 16 + fm;
                const int g = (kk * 4 + fkq) ^ (n & 7);
                bfr[ni] = *(const bf16x8*)(Bs + n * 64 + g * 8);
            }
#pragma unroll
            for (int mi = 0; mi < 4; ++mi)
#pragma unroll
                for (int ni = 0; ni < 4; ++ni)
                    acc[mi][ni] = __builtin_amdgcn_mfma_f32_16x16x32_bf16(
                        af[mi], bfr[ni], acc[mi][ni], 0, 0, 0);
        }
    }

    // epilogue: C/D layout col=lane&15, row=(lane>>4)*4+reg  (m89/m91 verified)
    const int colb = tileN + wn * 64 + fm;
#pragma unroll
    for (int mi = 0; mi < 4; ++mi) {
        const int rb = tileM + wm * 64 + mi * 16 + fkq * 4;
#pragma unroll
        for (int r = 0; r < 4; ++r) {
            const int row = rb + r;
            if (row < M) {
                unsigned short* dst = Sup + (long)row * D + colb;
#pragma unroll
                for (int ni = 0; ni < 4; ++ni)
                    dst[ni * 16] = f2bf(acc[mi][ni][r]);
            }
        }
    }
}

// ------------------------------------------- scatter: out[row] += val*Sup[col]
// one wave per edge; lane covers 8 columns (16B gather + 8 fp32 atomics)
__global__ __launch_bounds__(256) void scatter_kernel(const unsigned short* __restrict__ sup,
                                                      const int* __restrict__ erow,
                                                      const int* __restrict__ ecol,
                                                      const float* __restrict__ eval,
                                                      float* __restrict__ out,
                                                      int nE) {
    const int lane = threadIdx.x & 63;
    int wg = (int)((blockIdx.x * 256 + threadIdx.x) >> 6);
    const int nW = (gridDim.x * 256) >> 6;
    for (int e = wg; e < nE; e += nW) {
        const int r = erow[e];
        const int c = ecol[e];
        const float v = eval[e];
        const uint4 p = *(const uint4*)(sup + (long)c * D + lane * 8);
        float* dst = out + (long)r * D + lane * 8;
        const uint32_t pk[4] = {p.x, p.y, p.z, p.w};
#pragma unroll
        for (int i = 0; i < 4; ++i) {
            const float lo = __uint_as_float((pk[i] & 0x0000ffffu) << 16);
            const float hi = __uint_as_float(pk[i] & 0xffff0000u);
            unsafeAtomicAdd(dst + i * 2,     v * lo);
            unsafeAtomicAdd(dst + i * 2 + 1, v * hi);
        }
    }
}

extern "C" void kernel_launch(void* const* d_in, const int* in_sizes, int n_in,
                              void* d_out, int out_size, void* d_ws, size_t ws_size,
                              hipStream_t stream) {
    const float* x        = (const float*)d_in[0];
    const int*   adj_row  = (const int*)d_in[1];
    const int*   adj_col  = (const int*)d_in[2];
    const float* adj_vals = (const float*)d_in[3];
    const float* weight   = (const float*)d_in[4];
    const float* bias     = (const float*)d_in[5];
    float* out = (float*)d_out;

    const int M = in_sizes[0] / D;     // 100000 nodes
    const int E = in_sizes[1];         // 800000 edges

    // workspace layout
    char* ws = (char*)d_ws;
    unsigned short* Xb  = (unsigned short*)ws;                          // M*D bf16
    unsigned short* Sup = (unsigned short*)(ws + (size_t)M * D * 2);    // M*D bf16
    unsigned short* Wt  = (unsigned short*)(ws + (size_t)M * D * 4);    // D*D bf16

    // 1) X -> bf16
    {
        long n8 = (long)M * D / 8;
        int blocks = (int)((n8 + 255) / 256);
        cvt_x_kernel<<<blocks, 256, 0, stream>>>((const float4*)x, (uint4*)Xb, n8);
    }
    // 2) W -> Wt (transposed bf16)
    cvt_w_kernel<<<dim3(D / 32, D / 32), 256, 0, stream>>>(weight, Wt);
    // 3) out = b (bias folded into init)
    {
        long n4 = (long)M * D / 4;
        int blocks = (int)((n4 + 255) / 256);
        init_out_kernel<<<blocks, 256, 0, stream>>>((float4*)out, (const float4*)bias, n4);
    }
    // 4) Sup = Xb @ W  (bf16 MFMA)
    gemm_kernel<<<dim3((M + 127) / 128, D / 128), 256, 0, stream>>>(Xb, Wt, Sup, M);
    // 5) out[row] += val * Sup[col]
    scatter_kernel<<<8192, 256, 0, stream>>>(Sup, adj_row, adj_col, adj_vals, out, E);
}

// Round 2
// 732.407 us; speedup vs baseline: 15.5117x; 15.5117x over previous
//
#include <hip/hip_runtime.h>
#include <hip/hip_bf16.h>
#include <stdint.h>

#define D 512          // D_IN == D_OUT == 512
#define D4 (D / 4)

typedef __bf16 bf16x8 __attribute__((ext_vector_type(8)));
typedef float  f32x4  __attribute__((ext_vector_type(4)));

__device__ __forceinline__ unsigned short f2bf(float f) {
    uint32_t u = __float_as_uint(f);
    uint32_t r = u + 0x7fffu + ((u >> 16) & 1u);   // RNE
    return (unsigned short)(r >> 16);
}

__device__ __forceinline__ uint32_t pack2(float lo, float hi) {
    return (uint32_t)f2bf(lo) | ((uint32_t)f2bf(hi) << 16);
}

// ---------------------------------------------------------------- cvt X -> bf16
__global__ __launch_bounds__(256) void cvt_x_kernel(const float4* __restrict__ x,
                                                    uint4* __restrict__ xb,
                                                    long n8) {
    long i = (long)blockIdx.x * 256 + threadIdx.x;   // one thread = 8 elements
    if (i >= n8) return;
    float4 a = x[i * 2];
    float4 b = x[i * 2 + 1];
    uint4 o;
    o.x = pack2(a.x, a.y);
    o.y = pack2(a.z, a.w);
    o.z = pack2(b.x, b.y);
    o.w = pack2(b.z, b.w);
    xb[i] = o;
}

// ------------------------------------------------- transpose + cvt W -> Wt bf16
__global__ __launch_bounds__(256) void cvt_w_kernel(const float* __restrict__ w,
                                                    unsigned short* __restrict__ wt) {
    __shared__ float t[32][33];
    const int tx = threadIdx.x & 31;
    const int ty = threadIdx.x >> 5;       // 0..7
    const int n0 = blockIdx.x * 32;
    const int k0 = blockIdx.y * 32;
#pragma unroll
    for (int i = 0; i < 4; ++i)
        t[ty + i * 8][tx] = w[(long)(k0 + ty + i * 8) * D + n0 + tx];
    __syncthreads();
#pragma unroll
    for (int i = 0; i < 4; ++i)
        wt[(long)(n0 + ty + i * 8) * D + k0 + tx] = f2bf(t[tx][ty + i * 8]);
}

// ---------------------------------------------------------------- zero int buf
__global__ __launch_bounds__(256) void zero_kernel(int* __restrict__ p, int n) {
    int i = blockIdx.x * 256 + threadIdx.x;
    if (i < n) p[i] = 0;
}

// ------------------------------------------------------------ row histogram
__global__ __launch_bounds__(256) void hist_kernel(const int* __restrict__ erow,
                                                   int* __restrict__ cnt, int nE) {
    int i = blockIdx.x * 256 + threadIdx.x;
    int stride = gridDim.x * 256;
    for (; i < nE; i += stride) atomicAdd(&cnt[erow[i]], 1);
}

// ------------------------------------- single-block exclusive scan of cnt[M]
// writes rowptr[0..M] and heads[i] = rowptr[i]. heads MAY alias cnt (each
// element is read-then-written by the same thread).
__global__ __launch_bounds__(1024) void scan_kernel(const int* __restrict__ cnt,
                                                    int* __restrict__ rowptr,
                                                    int* __restrict__ heads,
                                                    int M) {
    __shared__ int wsum[16];
    __shared__ int wpre[16];
    __shared__ int s_carry;
    const int lane = threadIdx.x & 63;
    const int wv   = threadIdx.x >> 6;
    if (threadIdx.x == 0) s_carry = 0;
    __syncthreads();
    for (int base = 0; base < M; base += 1024) {
        const int i = base + (int)threadIdx.x;
        const int v = (i < M) ? cnt[i] : 0;
        int s = v;
#pragma unroll
        for (int off = 1; off < 64; off <<= 1) {
            int t = __shfl_up(s, off);
            if (lane >= off) s += t;
        }
        if (lane == 63) wsum[wv] = s;
        __syncthreads();
        if (threadIdx.x == 0) {
            int acc = s_carry;
#pragma unroll
            for (int j = 0; j < 16; ++j) { wpre[j] = acc; acc += wsum[j]; }
            s_carry = acc;
        }
        __syncthreads();
        const int excl = wpre[wv] + s - v;
        if (i < M) { rowptr[i] = excl; heads[i] = excl; }
        __syncthreads();
    }
    if (threadIdx.x == 0) rowptr[M] = s_carry;
}

// --------------------------------------- counting-sort edges by dest row
__global__ __launch_bounds__(256) void edge_sort_kernel(const int* __restrict__ erow,
                                                        const int* __restrict__ ecol,
                                                        const float* __restrict__ eval,
                                                        int* __restrict__ heads,
                                                        int* __restrict__ scol,
                                                        float* __restrict__ sval,
                                                        int nE) {
    int i = blockIdx.x * 256 + threadIdx.x;
    int stride = gridDim.x * 256;
    for (; i < nE; i += stride) {
        const int r = erow[i];
        const int p = atomicAdd(&heads[r], 1);
        scol[p] = ecol[i];
        sval[p] = eval[i];
    }
}

// --------------------------------------------------------- GEMM: Sup = Xb * W
// 128x128 tile, BK=64, 256 threads (4 waves, 2x2), 16x16x32 bf16 MFMA.
__global__ __launch_bounds__(256) void gemm_kernel(const unsigned short* __restrict__ Xb,
                                                   const unsigned short* __restrict__ Wt,
                                                   unsigned short* __restrict__ Sup,
                                                   int M) {
    __shared__ __align__(16) unsigned short As[128 * 64];
    __shared__ __align__(16) unsigned short Bs[128 * 64];
    const int tid  = threadIdx.x;
    const int wv   = tid >> 6;
    const int lane = tid & 63;
    const int tileM = blockIdx.x * 128;
    const int tileN = blockIdx.y * 128;
    const int wm = wv >> 1, wn = wv & 1;

    f32x4 acc[4][4];
#pragma unroll
    for (int i = 0; i < 4; ++i)
#pragma unroll
        for (int j = 0; j < 4; ++j) acc[i][j] = (f32x4)0.0f;

    const int srow = lane >> 3;               // row within chunk
    const int sgrn = (lane & 7) ^ srow;       // swizzled source granule
    const int scol = sgrn * 8;

    const int fm  = lane & 15;
    const int fkq = lane >> 4;                // 0..3

    for (int kt = 0; kt < D; kt += 64) {
        __syncthreads();
#pragma unroll
        for (int i = 0; i < 4; ++i) {
            const int c   = wv * 4 + i;
            const int row = c * 8 + srow;
            int rg = tileM + row;
            rg = (rg < M) ? rg : (M - 1);
            const unsigned short* ga = Xb + (long)rg * D + kt + scol;
            __builtin_amdgcn_global_load_lds(
                (const __attribute__((address_space(1))) void*)ga,
                (__attribute__((address_space(3))) void*)(As + c * 512), 16, 0, 0);
            const unsigned short* gb = Wt + (long)(tileN + row) * D + kt + scol;
            __builtin_amdgcn_global_load_lds(
                (const __attribute__((address_space(1))) void*)gb,
                (__attribute__((address_space(3))) void*)(Bs + c * 512), 16, 0, 0);
        }
        __syncthreads();
#pragma unroll
        for (int kk = 0; kk < 2; ++kk) {
            bf16x8 af[4], bfr[4];
#pragma unroll
            for (int mi = 0; mi < 4; ++mi) {
                const int m = wm * 64 + mi * 16 + fm;
                const int g = (kk * 4 + fkq) ^ (m & 7);
                af[mi] = *(const bf16x8*)(As + m * 64 + g * 8);
            }
#pragma unroll
            for (int ni = 0; ni < 4; ++ni) {
                const int n = wn * 64 + ni * 16 + fm;
                const int g = (kk * 4 + fkq) ^ (n & 7);
                bfr[ni] = *(const bf16x8*)(Bs + n * 64 + g * 8);
            }
#pragma unroll
            for (int mi = 0; mi < 4; ++mi)
#pragma unroll
                for (int ni = 0; ni < 4; ++ni)
                    acc[mi][ni] = __builtin_amdgcn_mfma_f32_16x16x32_bf16(
                        af[mi], bfr[ni], acc[mi][ni], 0, 0, 0);
        }
    }

    const int colb = tileN + wn * 64 + fm;
#pragma unroll
    for (int mi = 0; mi < 4; ++mi) {
        const int rb = tileM + wm * 64 + mi * 16 + fkq * 4;
#pragma unroll
        for (int r = 0; r < 4; ++r) {
            const int row = rb + r;
            if (row < M) {
                unsigned short* dst = Sup + (long)row * D + colb;
#pragma unroll
                for (int ni = 0; ni < 4; ++ni)
                    dst[ni * 16] = f2bf(acc[mi][ni][r]);
            }
        }
    }
}

// ----------------------------- pull aggregation: out[r] = b + sum val*Sup[col]
// one wave per row; lane covers 8 columns; acc in registers; no atomics.
__global__ __launch_bounds__(256) void aggregate_kernel(const unsigned short* __restrict__ sup,
                                                        const int* __restrict__ rowptr,
                                                        const int* __restrict__ scol,
                                                        const float* __restrict__ sval,
                                                        const float* __restrict__ bias,
                                                        float* __restrict__ out,
                                                        int M) {
    const int lane = threadIdx.x & 63;
    const int row  = (int)((blockIdx.x * 256 + threadIdx.x) >> 6);
    if (row >= M) return;
    const int beg = rowptr[row];
    const int end = rowptr[row + 1];

    const float4 b0 = ((const float4*)bias)[lane * 2];
    const float4 b1 = ((const float4*)bias)[lane * 2 + 1];
    float acc[8] = {b0.x, b0.y, b0.z, b0.w, b1.x, b1.y, b1.z, b1.w};

    for (int e = beg; e < end; ++e) {
        const int c   = scol[e];
        const float v = sval[e];
        const uint4 p = *(const uint4*)(sup + (long)c * D + lane * 8);
        const uint32_t pk[4] = {p.x, p.y, p.z, p.w};
#pragma unroll
        for (int i = 0; i < 4; ++i) {
            acc[i * 2]     += v * __uint_as_float((pk[i] & 0x0000ffffu) << 16);
            acc[i * 2 + 1] += v * __uint_as_float(pk[i] & 0xffff0000u);
        }
    }

    float4* dst = (float4*)(out + (long)row * D);
    dst[lane * 2]     = (float4){acc[0], acc[1], acc[2], acc[3]};
    dst[lane * 2 + 1] = (float4){acc[4], acc[5], acc[6], acc[7]};
}

extern "C" void kernel_launch(void* const* d_in, const int* in_sizes, int n_in,
                              void* d_out, int out_size, void* d_ws, size_t ws_size,
                              hipStream_t stream) {
    const float* x        = (const float*)d_in[0];
    const int*   adj_row  = (const int*)d_in[1];
    const int*   adj_col  = (const int*)d_in[2];
    const float* adj_vals = (const float*)d_in[3];
    const float* weight   = (const float*)d_in[4];
    const float* bias     = (const float*)d_in[5];
    float* out = (float*)d_out;

    const int M = in_sizes[0] / D;     // 100000 nodes
    const int E = in_sizes[1];         // 800000 edges

    // workspace layout (~213 MB)
    char* ws = (char*)d_ws;
    size_t off = 0;
    unsigned short* Xb  = (unsigned short*)(ws + off); off += (size_t)M * D * 2;
    unsigned short* Sup = (unsigned short*)(ws + off); off += (size_t)M * D * 2;
    unsigned short* Wt  = (unsigned short*)(ws + off); off += (size_t)D * D * 2;
    int*   rowptr = (int*)(ws + off);   off += (size_t)(M + 1) * 4;
    int*   heads  = (int*)(ws + off);   off += (size_t)M * 4;        // also the histogram
    int*   scol   = (int*)(ws + off);   off += (size_t)E * 4;
    float* sval   = (float*)(ws + off); off += (size_t)E * 4;
    int* cnt = heads;                   // histogram aliases heads

    // --- CSR construction (independent of GEMM chain) ---
    zero_kernel<<<(M + 255) / 256, 256, 0, stream>>>(cnt, M);
    hist_kernel<<<1024, 256, 0, stream>>>(adj_row, cnt, E);
    scan_kernel<<<1, 1024, 0, stream>>>(cnt, rowptr, heads, M);
    edge_sort_kernel<<<1024, 256, 0, stream>>>(adj_row, adj_col, adj_vals,
                                               heads, scol, sval, E);

    // --- dense chain ---
    {
        long n8 = (long)M * D / 8;
        cvt_x_kernel<<<(int)((n8 + 255) / 256), 256, 0, stream>>>(
            (const float4*)x, (uint4*)Xb, n8);
    }
    cvt_w_kernel<<<dim3(D / 32, D / 32), 256, 0, stream>>>(weight, Wt);
    gemm_kernel<<<dim3((M + 127) / 128, D / 128), 256, 0, stream>>>(Xb, Wt, Sup, M);

    // --- pull aggregation (no atomics) ---
    aggregate_kernel<<<(M * 64 + 255) / 256, 256, 0, stream>>>(
        Sup, rowptr, scol, sval, bias, out, M);
}